// Round 11
// baseline (264.007 us; speedup 1.0000x reference)
//
#include <hip/hip_runtime.h>
#include <math.h>

#define BB   64
#define CC   512
#define P2   49
#define CB   128
#define NB   3136   // BB * P2
#define TEMPI (1.0f/40.0f)

typedef __attribute__((ext_vector_type(4))) short    bf16x4;
typedef __attribute__((ext_vector_type(4))) float    f32x4;
typedef unsigned short u16;

__device__ inline u16 f2bf(float f) {
    union { float f; unsigned u; } x{f};
    unsigned r = (x.u + 0x7FFFu + ((x.u >> 16) & 1u)) >> 16;
    return (u16)r;
}

__device__ inline f32x4 mfma16x16(bf16x4 a, bf16x4 b, f32x4 c) {
#if __has_builtin(__builtin_amdgcn_mfma_f32_16x16x16bf16_1k)
    return __builtin_amdgcn_mfma_f32_16x16x16bf16_1k(a, b, c, 0, 0, 0);
#elif __has_builtin(__builtin_amdgcn_mfma_f32_16x16x16_bf16)
    return __builtin_amdgcn_mfma_f32_16x16x16_bf16(a, b, c, 0, 0, 0);
#else
    f32x4 d;
    asm("v_mfma_f32_16x16x16_bf16 %0, %1, %2, %3"
        : "=v"(d) : "v"(a), "v"(b), "v"(c));
    return d;
#endif
}

// ---------------------------------------------------------------------------
// 1) avg-pool 28x28 -> 7x7 + BatchNorm(eval)  -> pfT[c][b*49+p]  (fp32)
// ---------------------------------------------------------------------------
__global__ __launch_bounds__(256) void pool_bn_k(
    const float* __restrict__ x, const float* __restrict__ g,
    const float* __restrict__ be, const float* __restrict__ mu,
    const float* __restrict__ var, float* __restrict__ pfT)
{
    int idx = blockIdx.x * 256 + threadIdx.x;
    int p  = idx % 49;
    int bc = idx / 49;          // b*512 + c
    int c  = bc & 511;
    int b  = bc >> 9;
    int py = p / 7, px = p % 7;
    const float* base = x + (size_t)bc * 784 + py * 4 * 28 + px * 4;
    float s = 0.f;
#pragma unroll
    for (int r = 0; r < 4; ++r) {
        float4 v = *(const float4*)(base + r * 28);
        s += v.x + v.y + v.z + v.w;
    }
    s *= (1.f / 16.f);
    float sc = g[c] * rsqrtf(var[c] + 1e-5f);
    pfT[(size_t)c * NB + b * 49 + p] = (s - mu[c]) * sc + be[c];
}

// ---------------------------------------------------------------------------
// 2a) repack pf fp32 -> A-operand fragments (bf16):
//     unit i = ((b*32+ct)*4+q)*64 + l : pf[ct*16+(l>>4)*4+j][b*49 + q*16+(l&15)]
// ---------------------------------------------------------------------------
__global__ __launch_bounds__(256) void repack_pf_k(
    const float* __restrict__ pfT, u16* __restrict__ dst)
{
    int i = blockIdx.x * 256 + threadIdx.x;   // 524288 units
    int l  = i & 63;
    int q  = (i >> 6) & 3;
    int ct = (i >> 8) & 31;
    int b  = i >> 13;
    int p  = q * 16 + (l & 15);
    int c0 = ct * 16 + ((l >> 4) << 2);
    ushort4 u;
    if (p < 49) {
        const float* s = pfT + (size_t)c0 * NB + b * 49 + p;
        u.x = f2bf(s[0]); u.y = f2bf(s[NB]);
        u.z = f2bf(s[2 * NB]); u.w = f2bf(s[3 * NB]);
    } else {
        u.x = u.y = u.z = u.w = 0;
    }
    ((ushort4*)dst)[i] = u;
}

// 2b) repack W[512][512] fp32 -> B-operand fragments (bf16):
//     unit i = (t*32+ct)*64 + l : W[t*16+(l&15)][ct*16+(l>>4)*4+j]
__global__ __launch_bounds__(256) void repack_w_k(
    const float* __restrict__ W, u16* __restrict__ dst)
{
    int i = blockIdx.x * 256 + threadIdx.x;   // 65536 units
    int l  = i & 63;
    int ct = (i >> 6) & 31;
    int t  = i >> 11;
    int o  = t * 16 + (l & 15);
    int c0 = ct * 16 + ((l >> 4) << 2);
    float4 v = *(const float4*)(W + (size_t)o * 512 + c0);
    ushort4 u;
    u.x = f2bf(v.x); u.y = f2bf(v.y); u.z = f2bf(v.z); u.w = f2bf(v.w);
    ((ushort4*)dst)[i] = u;
}

// 2c) MFMA GEMM in fragment space: dstF = W x pf, written directly as
//     attention Q/K fragments. Wave w -> chan-tile t = bx*4+w; b = by.
__global__ __launch_bounds__(256) void gemm_frag_k(
    const u16* __restrict__ pfF, const u16* __restrict__ WF,
    u16* __restrict__ dstF)
{
    int tid  = threadIdx.x;
    int lane = tid & 63;
    int w    = tid >> 6;
    int b    = blockIdx.y;
    int t    = blockIdx.x * 4 + w;

    const bf16x4* Ab = (const bf16x4*)pfF + (size_t)b * 8192 + lane;
    const bf16x4* Bw = (const bf16x4*)WF + (size_t)t * 2048 + lane;

    f32x4 acc[4];
#pragma unroll
    for (int q = 0; q < 4; ++q) acc[q] = (f32x4)0.f;

#pragma unroll
    for (int ct = 0; ct < 32; ++ct) {
        bf16x4 wv = Bw[ct * 64];
        bf16x4 a0 = Ab[(ct * 4 + 0) * 64];
        bf16x4 a1 = Ab[(ct * 4 + 1) * 64];
        bf16x4 a2 = Ab[(ct * 4 + 2) * 64];
        bf16x4 a3 = Ab[(ct * 4 + 3) * 64];
        acc[0] = mfma16x16(a0, wv, acc[0]);
        acc[1] = mfma16x16(a1, wv, acc[1]);
        acc[2] = mfma16x16(a2, wv, acc[2]);
        acc[3] = mfma16x16(a3, wv, acc[3]);
    }

#pragma unroll
    for (int q = 0; q < 4; ++q) {
        ushort4 u;
        u.x = f2bf(acc[q][0]); u.y = f2bf(acc[q][1]);
        u.z = f2bf(acc[q][2]); u.w = f2bf(acc[q][3]);
        ((ushort4*)dstF)[(((size_t)b * 32 + t) * 4 + q) * 64 + lane] = u;
    }
}

// ---------------------------------------------------------------------------
// 3) Vt[c][b*49+k] = sum_p pfT[c][b*49+p] * Wkern[k][p]   (bf16 out)
// ---------------------------------------------------------------------------
__global__ __launch_bounds__(256) void kwv_k(
    const float* __restrict__ pfT, const float* __restrict__ Wkern,
    u16* __restrict__ Vt)
{
    __shared__ float wk[2401];
    for (int l = threadIdx.x; l < 2401; l += 256) wk[l] = Wkern[l];
    __syncthreads();
    int idx = blockIdx.x * 256 + threadIdx.x;
    int k  = idx % 49;
    int cb = idx / 49;
    int base = (cb >> 6) * NB + (cb & 63) * 49;
    float s = 0.f;
#pragma unroll
    for (int p = 0; p < 49; ++p)
        s = fmaf(pfT[base + p], wk[k * 49 + p], s);
    Vt[base + k] = f2bf(s);
}

// repack V -> fragment layout
__global__ __launch_bounds__(256) void repack_v_k(
    const u16* __restrict__ src, u16* __restrict__ dst)
{
    int i = blockIdx.x * 256 + threadIdx.x;
    int l = i & 63;
    int pt = (i >> 6) & 3;
    int t = (i >> 8) & 31;
    int b = i >> 13;
    int p = pt * 16 + (l & 15);
    int d0 = t * 16 + ((l >> 4) << 2);
    ushort4 u;
    if (p < 49) {
        const u16* s = src + (size_t)d0 * NB + b * 49 + p;
        u.x = s[0]; u.y = s[NB]; u.z = s[2 * NB]; u.w = s[3 * NB];
    } else {
        u.x = u.y = u.z = u.w = 0;
    }
    ((ushort4*)dst)[i] = u;
}

// ---------------------------------------------------------------------------
// 4) MFMA flash attention (no-max softmax: scores/40 are O(1))
// ---------------------------------------------------------------------------
__global__ __launch_bounds__(256) void attn_mfma_k(
    const u16* __restrict__ QF, const u16* __restrict__ KF,
    const u16* __restrict__ VF, float* __restrict__ Ot)
{
    int tid  = threadIdx.x;
    int lane = tid & 63;
    int w    = tid >> 6;
    int b    = blockIdx.y;
    int ct   = blockIdx.x * 4 + w;

    const bf16x4* QFp = (const bf16x4*)QF + (size_t)b * 8192 + ct * 256 + lane;
    const bf16x4* KFp = (const bf16x4*)KF + (size_t)b * 8192 + lane;
    const bf16x4* VFp = (const bf16x4*)VF + (size_t)b * 8192 + lane;

    bf16x4 qf[4];
#pragma unroll
    for (int q = 0; q < 4; ++q) qf[q] = QFp[q * 64];

    f32x4 o[4];
#pragma unroll
    for (int pt = 0; pt < 4; ++pt) o[pt] = (f32x4)0.f;
    float lsum = 0.f;

    bf16x4 kf[4], vf[4], kn[4], vn[4];
#pragma unroll
    for (int q = 0; q < 4; ++q) { kf[q] = KFp[q * 64]; vf[q] = VFp[q * 64]; }

    for (int t = 0; t < 32; ++t) {
        if (t < 31) {
            const bf16x4* kp = KFp + (t + 1) * 256;
            const bf16x4* vp = VFp + (t + 1) * 256;
#pragma unroll
            for (int q = 0; q < 4; ++q) { kn[q] = kp[q * 64]; vn[q] = vp[q * 64]; }
        }
        f32x4 s = (f32x4)0.f;
#pragma unroll
        for (int q = 0; q < 4; ++q) s = mfma16x16(kf[q], qf[q], s);

        bf16x4 pa;
#pragma unroll
        for (int r = 0; r < 4; ++r) {
            float pe = __expf(s[r] * TEMPI);
            lsum += pe;
            pa[r] = (short)f2bf(pe);
        }
#pragma unroll
        for (int pt = 0; pt < 4; ++pt) o[pt] = mfma16x16(pa, vf[pt], o[pt]);

#pragma unroll
        for (int q = 0; q < 4; ++q) { kf[q] = kn[q]; vf[q] = vn[q]; }
    }

    lsum += __shfl_xor(lsum, 16);
    lsum += __shfl_xor(lsum, 32);
    float linv = 1.f / lsum;

    int g4 = (lane >> 4) << 2;
#pragma unroll
    for (int r = 0; r < 4; ++r) {
        float rl = __shfl(linv, g4 + r);
        int c = ct * 16 + g4 + r;
        float* op = Ot + (size_t)c * NB + b * 49;
#pragma unroll
        for (int pt = 0; pt < 4; ++pt) {
            int p = pt * 16 + (lane & 15);
            if (p < 49) op[p] = o[pt][r] * rl;
        }
    }
}

// ---------------------------------------------------------------------------
// 5) fp32 GEMM (small fusion convs): C[M][3136]=A[M][Kd]*Bm + bias
// ---------------------------------------------------------------------------
template <typename OT>
__global__ __launch_bounds__(256) void gemm64_k(
    const float* __restrict__ A, const float* __restrict__ Bm,
    OT* __restrict__ Cm, const float* __restrict__ bias, int M, int Kd)
{
    __shared__ float As[16][68];
    __shared__ float Bs[16][68];
    int tid = threadIdx.x;
    int tx = tid & 15, ty = tid >> 4;
    int n0 = blockIdx.x * 64, m0 = blockIdx.y * 64;
    float acc[4][4] = {};
    for (int k0 = 0; k0 < Kd; k0 += 16) {
#pragma unroll
        for (int r = 0; r < 4; ++r) {
            int l = tid + 256 * r;
            As[l & 15][l >> 4] = A[(m0 + (l >> 4)) * Kd + k0 + (l & 15)];
        }
#pragma unroll
        for (int r = 0; r < 4; ++r) {
            int l = tid + 256 * r;
            Bs[l >> 6][l & 63] = Bm[(size_t)(k0 + (l >> 6)) * NB + n0 + (l & 63)];
        }
        __syncthreads();
#pragma unroll
        for (int kk = 0; kk < 16; ++kk) {
            float4 a4 = *(const float4*)&As[kk][ty * 4];
            float4 b4 = *(const float4*)&Bs[kk][tx * 4];
            float av[4] = {a4.x, a4.y, a4.z, a4.w};
            float bv[4] = {b4.x, b4.y, b4.z, b4.w};
#pragma unroll
            for (int i = 0; i < 4; ++i)
#pragma unroll
                for (int j = 0; j < 4; ++j)
                    acc[i][j] = fmaf(av[i], bv[j], acc[i][j]);
        }
        __syncthreads();
    }
#pragma unroll
    for (int i = 0; i < 4; ++i) {
        int m = m0 + ty * 4 + i;
        float bb = bias ? bias[m] : 0.f;
        float4 o;
        o.x = acc[i][0] + bb; o.y = acc[i][1] + bb;
        o.z = acc[i][2] + bb; o.w = acc[i][3] + bb;
        *(float4*)((float*)Cm + (size_t)m * NB + n0 + tx * 4) = o;
    }
}

// ---------------------------------------------------------------------------
// 6) LayerNorm over (Cb=128, 49) per batch + tanh
// ---------------------------------------------------------------------------
__global__ __launch_bounds__(256) void ln_tanh_k(
    const float* __restrict__ F0, const float* __restrict__ lnw,
    const float* __restrict__ lnb, float* __restrict__ G)
{
    int b = blockIdx.x, tid = threadIdx.x;
    float s = 0.f, sq = 0.f;
    for (int e = tid; e < CB * 49; e += 256) {
        int o = e / 49, k = e - o * 49;
        float v = F0[o * NB + b * 49 + k];
        s += v; sq += v * v;
    }
#pragma unroll
    for (int off = 32; off > 0; off >>= 1) {
        s  += __shfl_xor(s, off);
        sq += __shfl_xor(sq, off);
    }
    __shared__ float rs[4], rq[4];
    __shared__ float smu, srstd;
    int wv = tid >> 6;
    if ((tid & 63) == 0) { rs[wv] = s; rq[wv] = sq; }
    __syncthreads();
    if (tid == 0) {
        float S = rs[0] + rs[1] + rs[2] + rs[3];
        float Q = rq[0] + rq[1] + rq[2] + rq[3];
        float mu = S / 6272.f;
        float v  = Q / 6272.f - mu * mu;
        smu = mu; srstd = rsqrtf(v + 1e-5f);
    }
    __syncthreads();
    float mu = smu, rstd = srstd;
    for (int e = tid; e < CB * 49; e += 256) {
        int o = e / 49, k = e - o * 49;
        int a = o * NB + b * 49 + k;
        G[a] = tanhf((F0[a] - mu) * rstd * lnw[e] + lnb[e]);
    }
}

// ---------------------------------------------------------------------------
// 7) dynamic depthwise 7x7 conv -- wave-per-plane, weights in SGPRs,
//    NO LDS: windows read directly from global (L2-resident; plane working
//    set ~2.8MB/XCD). Rationale: the [64-lane ds_read_b128 x 49-lane tile]
//    pattern is inherently ~6-way bank-conflicted (SQ_LDS_BANK_CONFLICT
//    ~2.4e7 = ~half of kernel cycles, invariant across 5 layout/VGPR/SGPR
//    variants). Boundary quads predicated to zero.
// ---------------------------------------------------------------------------
__global__ __launch_bounds__(256) void dwconv_k(
    const float* __restrict__ x, const float* __restrict__ KernT,
    float* __restrict__ out)
{
    int tid  = threadIdx.x;
    int lane = tid & 63;
    int wid  = tid >> 6;
    int P    = blockIdx.x * 4 + wid;  // plane = b*512 + c, grid exact
    int b = P >> 9, c = P & 511;

    // weight: lane i holds w[i]; readlane -> SGPRs (uniform per wave)
    float wvl = 0.f;
    if (lane < 49) wvl = KernT[(size_t)c * NB + b * 49 + lane];
    int wvi = __float_as_int(wvl);
    float w[49];
#pragma unroll
    for (int i = 0; i < 49; ++i)
        w[i] = __int_as_float(__builtin_amdgcn_readlane(wvi, i));

    if (lane >= 49) return;
    int ty = lane / 7, gx = lane - ty * 7;
    int y0 = 4 * ty, x0 = 4 * gx;
    const float* src = x + (size_t)P * 784;
    float acc[4][4] = {};

    const f32x4 z4 = (f32x4)0.f;
#pragma unroll
    for (int yy = 0; yy < 10; ++yy) {
        int ry = y0 + yy - 3;
        bool rok = (ry >= 0) && (ry < 28);
        const float* rb = src + ry * 28;
        // window cols x0-4 .. x0+7 (f[1..10] used); edge quads predicated
        f32x4 qa = (rok && x0 >= 4)  ? *(const f32x4*)(rb + x0 - 4) : z4;
        f32x4 qb = rok               ? *(const f32x4*)(rb + x0)     : z4;
        f32x4 qc = (rok && x0 < 24)  ? *(const f32x4*)(rb + x0 + 4) : z4;
        float f[12] = {qa.x, qa.y, qa.z, qa.w, qb.x, qb.y, qb.z, qb.w,
                       qc.x, qc.y, qc.z, qc.w};
#pragma unroll
        for (int j = 0; j < 4; ++j) {
            int dy = yy - j;
            if (dy < 0 || dy > 6) continue;
#pragma unroll
            for (int dx = 0; dx < 7; ++dx) {
                float wv = w[dy * 7 + dx];
                acc[j][0] = fmaf(wv, f[dx + 1], acc[j][0]);
                acc[j][1] = fmaf(wv, f[dx + 2], acc[j][1]);
                acc[j][2] = fmaf(wv, f[dx + 3], acc[j][2]);
                acc[j][3] = fmaf(wv, f[dx + 4], acc[j][3]);
            }
        }
    }

    float* op = out + (size_t)P * 784;
#pragma unroll
    for (int j = 0; j < 4; ++j) {
        float4 o4 = {acc[j][0], acc[j][1], acc[j][2], acc[j][3]};
        *(float4*)(op + (y0 + j) * 28 + x0) = o4;
    }
}

// ---------------------------------------------------------------------------
extern "C" void kernel_launch(void* const* d_in, const int* in_sizes, int n_in,
                              void* d_out, int out_size, void* d_ws, size_t ws_size,
                              hipStream_t stream)
{
    const float* x     = (const float*)d_in[0];
    const float* bng   = (const float*)d_in[1];
    const float* bnb   = (const float*)d_in[2];
    const float* bnm   = (const float*)d_in[3];
    const float* bnv   = (const float*)d_in[4];
    const float* Wq    = (const float*)d_in[5];
    const float* Wk    = (const float*)d_in[6];
    const float* Wkern = (const float*)d_in[7];
    const float* Wf0   = (const float*)d_in[8];
    const float* bf0   = (const float*)d_in[9];
    const float* lnw   = (const float*)d_in[10];
    const float* lnb   = (const float*)d_in[11];
    const float* Wf1   = (const float*)d_in[12];
    const float* bf1   = (const float*)d_in[13];
    float* out = (float*)d_out;
    float* ws  = (float*)d_ws;

    // workspace map (float offsets), peak 6,864,896 floats = 27.5 MB
    float* pfT = ws;                         // [0        .. 1,605,632)
    u16*   pfF = (u16*)(ws + 1605632);       // [1,605,632.. 2,654,208)
    u16*   WqF = (u16*)(ws + 2654208);       // [2,654,208.. 2,785,280)
    u16*   WkF = (u16*)(ws + 2785280);       // [2,785,280.. 2,916,352)
    u16*   Vt  = (u16*)(ws + 2916352);       // [2,916,352.. 3,719,168)  802,816 f
    u16*   QF  = (u16*)(ws + 3719168);       // [3,719,168.. 4,767,744)
    u16*   KF  = (u16*)(ws + 4767744);       // [4,767,744.. 5,816,320)
    u16*   VF  = (u16*)(ws + 5816320);       // [5,816,320.. 6,864,896)
    float* Ot    = ws;                       // reuses pfT  (dead after kwv/repacks)
    float* F0    = ws + 1605632;             // reuses pfF  (dead after gemm_frag)
    float* G     = ws + 2007040;             //   "
    float* KernT = ws + 2654208;             // reuses WF/Vt/QF (dead after attn)

    pool_bn_k<<<6272, 256, 0, stream>>>(x, bng, bnb, bnm, bnv, pfT);
    repack_pf_k<<<2048, 256, 0, stream>>>(pfT, pfF);
    repack_w_k<<<256, 256, 0, stream>>>(Wq, WqF);
    repack_w_k<<<256, 256, 0, stream>>>(Wk, WkF);
    kwv_k<<<6272, 256, 0, stream>>>(pfT, Wkern, Vt);
    gemm_frag_k<<<dim3(8, 64), 256, 0, stream>>>(pfF, WqF, QF);
    gemm_frag_k<<<dim3(8, 64), 256, 0, stream>>>(pfF, WkF, KF);
    repack_v_k<<<2048, 256, 0, stream>>>(Vt, VF);
    attn_mfma_k<<<dim3(8, 64), 256, 0, stream>>>(QF, KF, VF, Ot);
    gemm64_k<float><<<dim3(49, 2), 256, 0, stream>>>(Wf0, Ot, F0, bf0, 128, 512);
    ln_tanh_k<<<64, 256, 0, stream>>>(F0, lnw, lnb, G);
    gemm64_k<float><<<dim3(49, 8), 256, 0, stream>>>(Wf1, G, KernT, bf1, 512, 128);
    dwconv_k<<<8192, 256, 0, stream>>>(x, KernT, out);
}

// Round 13
// 196.156 us; speedup vs baseline: 1.3459x; 1.3459x over previous
//
#include <hip/hip_runtime.h>
#include <math.h>

#define BB   64
#define CC   512
#define P2   49
#define CB   128
#define NB   3136   // BB * P2
#define TEMPI (1.0f/40.0f)

typedef __attribute__((ext_vector_type(4))) short    bf16x4;
typedef __attribute__((ext_vector_type(4))) float    f32x4;
typedef unsigned short u16;

__device__ inline u16 f2bf(float f) {
    union { float f; unsigned u; } x{f};
    unsigned r = (x.u + 0x7FFFu + ((x.u >> 16) & 1u)) >> 16;
    return (u16)r;
}

__device__ inline f32x4 mfma16x16(bf16x4 a, bf16x4 b, f32x4 c) {
#if __has_builtin(__builtin_amdgcn_mfma_f32_16x16x16bf16_1k)
    return __builtin_amdgcn_mfma_f32_16x16x16bf16_1k(a, b, c, 0, 0, 0);
#elif __has_builtin(__builtin_amdgcn_mfma_f32_16x16x16_bf16)
    return __builtin_amdgcn_mfma_f32_16x16x16_bf16(a, b, c, 0, 0, 0);
#else
    f32x4 d;
    asm("v_mfma_f32_16x16x16_bf16 %0, %1, %2, %3"
        : "=v"(d) : "v"(a), "v"(b), "v"(c));
    return d;
#endif
}

// ---------------------------------------------------------------------------
// 1) avg-pool 28x28 -> 7x7 + BatchNorm(eval)  -> pfT[c][b*49+p]  (fp32)
// ---------------------------------------------------------------------------
__global__ __launch_bounds__(256) void pool_bn_k(
    const float* __restrict__ x, const float* __restrict__ g,
    const float* __restrict__ be, const float* __restrict__ mu,
    const float* __restrict__ var, float* __restrict__ pfT)
{
    int idx = blockIdx.x * 256 + threadIdx.x;
    int p  = idx % 49;
    int bc = idx / 49;          // b*512 + c
    int c  = bc & 511;
    int b  = bc >> 9;
    int py = p / 7, px = p % 7;
    const float* base = x + (size_t)bc * 784 + py * 4 * 28 + px * 4;
    float s = 0.f;
#pragma unroll
    for (int r = 0; r < 4; ++r) {
        float4 v = *(const float4*)(base + r * 28);
        s += v.x + v.y + v.z + v.w;
    }
    s *= (1.f / 16.f);
    float sc = g[c] * rsqrtf(var[c] + 1e-5f);
    pfT[(size_t)c * NB + b * 49 + p] = (s - mu[c]) * sc + be[c];
}

// ---------------------------------------------------------------------------
// 2a) repack pf fp32 -> A-operand fragments (bf16):
//     unit i = ((b*32+ct)*4+q)*64 + l : pf[ct*16+(l>>4)*4+j][b*49 + q*16+(l&15)]
// ---------------------------------------------------------------------------
__global__ __launch_bounds__(256) void repack_pf_k(
    const float* __restrict__ pfT, u16* __restrict__ dst)
{
    int i = blockIdx.x * 256 + threadIdx.x;   // 524288 units
    int l  = i & 63;
    int q  = (i >> 6) & 3;
    int ct = (i >> 8) & 31;
    int b  = i >> 13;
    int p  = q * 16 + (l & 15);
    int c0 = ct * 16 + ((l >> 4) << 2);
    ushort4 u;
    if (p < 49) {
        const float* s = pfT + (size_t)c0 * NB + b * 49 + p;
        u.x = f2bf(s[0]); u.y = f2bf(s[NB]);
        u.z = f2bf(s[2 * NB]); u.w = f2bf(s[3 * NB]);
    } else {
        u.x = u.y = u.z = u.w = 0;
    }
    ((ushort4*)dst)[i] = u;
}

// 2b) repack W[M][K] fp32 -> B-operand fragments (bf16), K passed in:
//     unit i = (t*(K/16)+ct)*64 + l : W[t*16+(l&15)][ct*16+(l>>4)*4+j]
__global__ __launch_bounds__(256) void repack_w_k(
    const float* __restrict__ W, u16* __restrict__ dst, int K)
{
    int i = blockIdx.x * 256 + threadIdx.x;
    int l  = i & 63;
    int KT = K >> 4;
    int ct = (i >> 6) % KT;
    int t  = (i >> 6) / KT;
    int o  = t * 16 + (l & 15);
    int c0 = ct * 16 + ((l >> 4) << 2);
    float4 v = *(const float4*)(W + (size_t)o * K + c0);
    ushort4 u;
    u.x = f2bf(v.x); u.y = f2bf(v.y); u.z = f2bf(v.z); u.w = f2bf(v.w);
    ((ushort4*)dst)[i] = u;
}

// 2c) MFMA GEMM in fragment space: dstF = W x pf, written directly as
//     attention Q/K fragments. Wave w -> chan-tile t = bx*4+w; b = by.
__global__ __launch_bounds__(256) void gemm_frag_k(
    const u16* __restrict__ pfF, const u16* __restrict__ WF,
    u16* __restrict__ dstF)
{
    int tid  = threadIdx.x;
    int lane = tid & 63;
    int w    = tid >> 6;
    int b    = blockIdx.y;
    int t    = blockIdx.x * 4 + w;

    const bf16x4* Ab = (const bf16x4*)pfF + (size_t)b * 8192 + lane;
    const bf16x4* Bw = (const bf16x4*)WF + (size_t)t * 2048 + lane;

    f32x4 acc[4];
#pragma unroll
    for (int q = 0; q < 4; ++q) acc[q] = (f32x4)0.f;

#pragma unroll
    for (int ct = 0; ct < 32; ++ct) {
        bf16x4 wv = Bw[ct * 64];
        bf16x4 a0 = Ab[(ct * 4 + 0) * 64];
        bf16x4 a1 = Ab[(ct * 4 + 1) * 64];
        bf16x4 a2 = Ab[(ct * 4 + 2) * 64];
        bf16x4 a3 = Ab[(ct * 4 + 3) * 64];
        acc[0] = mfma16x16(a0, wv, acc[0]);
        acc[1] = mfma16x16(a1, wv, acc[1]);
        acc[2] = mfma16x16(a2, wv, acc[2]);
        acc[3] = mfma16x16(a3, wv, acc[3]);
    }

#pragma unroll
    for (int q = 0; q < 4; ++q) {
        ushort4 u;
        u.x = f2bf(acc[q][0]); u.y = f2bf(acc[q][1]);
        u.z = f2bf(acc[q][2]); u.w = f2bf(acc[q][3]);
        ((ushort4*)dstF)[(((size_t)b * 32 + t) * 4 + q) * 64 + lane] = u;
    }
}

// ---------------------------------------------------------------------------
// 2d) fragment GEMM with fp32 standard-layout output + bias.
//     A = data fragments (A[row][kk] = X[cin=ct*16+kk][p=q*16+row]) so
//     D[row][col] = Cout[c = t*16+col][p = q*16+row]  -- NOTE col->c, row->p
//     (round-12 bug: epilogue used attn's row->c mapping; transposed output).
// ---------------------------------------------------------------------------
template <int KT>
__global__ __launch_bounds__(256) void fusion_frag_k(
    const u16* __restrict__ AF, const u16* __restrict__ WF,
    float* __restrict__ Cout, const float* __restrict__ bias)
{
    int tid  = threadIdx.x;
    int lane = tid & 63;
    int w    = tid >> 6;
    int b    = blockIdx.y;
    int t    = blockIdx.x * 4 + w;

    const bf16x4* Ab = (const bf16x4*)AF + (size_t)b * (KT * 256) + lane;
    const bf16x4* Bw = (const bf16x4*)WF + (size_t)t * (KT * 64) + lane;

    f32x4 acc[4];
#pragma unroll
    for (int q = 0; q < 4; ++q) acc[q] = (f32x4)0.f;

#pragma unroll
    for (int ct = 0; ct < KT; ++ct) {
        bf16x4 wv = Bw[ct * 64];
        bf16x4 a0 = Ab[(ct * 4 + 0) * 64];
        bf16x4 a1 = Ab[(ct * 4 + 1) * 64];
        bf16x4 a2 = Ab[(ct * 4 + 2) * 64];
        bf16x4 a3 = Ab[(ct * 4 + 3) * 64];
        acc[0] = mfma16x16(a0, wv, acc[0]);
        acc[1] = mfma16x16(a1, wv, acc[1]);
        acc[2] = mfma16x16(a2, wv, acc[2]);
        acc[3] = mfma16x16(a3, wv, acc[3]);
    }

    // corrected epilogue: c = t*16 + col(lane&15), p = q*16 + row(g4+r)
    int c = t * 16 + (lane & 15);
    float bb = bias[c];
    float* op = Cout + (size_t)c * NB + b * 49;
    int g4 = (lane >> 4) << 2;
#pragma unroll
    for (int q = 0; q < 4; ++q) {
#pragma unroll
        for (int r = 0; r < 4; ++r) {
            int p = q * 16 + g4 + r;
            if (p < 49) op[p] = acc[q][r] + bb;
        }
    }
}

// ---------------------------------------------------------------------------
// 3) Vt[c][b*49+k] = sum_p pfT[c][b*49+p] * Wkern[k][p]   (bf16 out)
// ---------------------------------------------------------------------------
__global__ __launch_bounds__(256) void kwv_k(
    const float* __restrict__ pfT, const float* __restrict__ Wkern,
    u16* __restrict__ Vt)
{
    __shared__ float wk[2401];
    for (int l = threadIdx.x; l < 2401; l += 256) wk[l] = Wkern[l];
    __syncthreads();
    int idx = blockIdx.x * 256 + threadIdx.x;
    int k  = idx % 49;
    int cb = idx / 49;
    int base = (cb >> 6) * NB + (cb & 63) * 49;
    float s = 0.f;
#pragma unroll
    for (int p = 0; p < 49; ++p)
        s = fmaf(pfT[base + p], wk[k * 49 + p], s);
    Vt[base + k] = f2bf(s);
}

// repack V -> fragment layout
__global__ __launch_bounds__(256) void repack_v_k(
    const u16* __restrict__ src, u16* __restrict__ dst)
{
    int i = blockIdx.x * 256 + threadIdx.x;
    int l = i & 63;
    int pt = (i >> 6) & 3;
    int t = (i >> 8) & 31;
    int b = i >> 13;
    int p = pt * 16 + (l & 15);
    int d0 = t * 16 + ((l >> 4) << 2);
    ushort4 u;
    if (p < 49) {
        const u16* s = src + (size_t)d0 * NB + b * 49 + p;
        u.x = s[0]; u.y = s[NB]; u.z = s[2 * NB]; u.w = s[3 * NB];
    } else {
        u.x = u.y = u.z = u.w = 0;
    }
    ((ushort4*)dst)[i] = u;
}

// ---------------------------------------------------------------------------
// 4) MFMA flash attention; output written DIRECTLY as bf16 A-fragments
//    (o[pt][r] at (c=ct*16+(l>>4)*4+r, p=pt*16+(l&15)) == fragment map).
// ---------------------------------------------------------------------------
__global__ __launch_bounds__(256) void attn_mfma_k(
    const u16* __restrict__ QF, const u16* __restrict__ KF,
    const u16* __restrict__ VF, u16* __restrict__ OtF)
{
    int tid  = threadIdx.x;
    int lane = tid & 63;
    int w    = tid >> 6;
    int b    = blockIdx.y;
    int ct   = blockIdx.x * 4 + w;

    const bf16x4* QFp = (const bf16x4*)QF + (size_t)b * 8192 + ct * 256 + lane;
    const bf16x4* KFp = (const bf16x4*)KF + (size_t)b * 8192 + lane;
    const bf16x4* VFp = (const bf16x4*)VF + (size_t)b * 8192 + lane;

    bf16x4 qf[4];
#pragma unroll
    for (int q = 0; q < 4; ++q) qf[q] = QFp[q * 64];

    f32x4 o[4];
#pragma unroll
    for (int pt = 0; pt < 4; ++pt) o[pt] = (f32x4)0.f;
    float lsum = 0.f;

    bf16x4 kf[4], vf[4], kn[4], vn[4];
#pragma unroll
    for (int q = 0; q < 4; ++q) { kf[q] = KFp[q * 64]; vf[q] = VFp[q * 64]; }

    for (int t = 0; t < 32; ++t) {
        if (t < 31) {
            const bf16x4* kp = KFp + (t + 1) * 256;
            const bf16x4* vp = VFp + (t + 1) * 256;
#pragma unroll
            for (int q = 0; q < 4; ++q) { kn[q] = kp[q * 64]; vn[q] = vp[q * 64]; }
        }
        f32x4 s = (f32x4)0.f;
#pragma unroll
        for (int q = 0; q < 4; ++q) s = mfma16x16(kf[q], qf[q], s);

        bf16x4 pa;
#pragma unroll
        for (int r = 0; r < 4; ++r) {
            float pe = __expf(s[r] * TEMPI);
            lsum += pe;
            pa[r] = (short)f2bf(pe);
        }
#pragma unroll
        for (int pt = 0; pt < 4; ++pt) o[pt] = mfma16x16(pa, vf[pt], o[pt]);

#pragma unroll
        for (int q = 0; q < 4; ++q) { kf[q] = kn[q]; vf[q] = vn[q]; }
    }

    lsum += __shfl_xor(lsum, 16);
    lsum += __shfl_xor(lsum, 32);
    float linv = 1.f / lsum;

    int g4 = (lane >> 4) << 2;
    float rl0 = __shfl(linv, g4 + 0);
    float rl1 = __shfl(linv, g4 + 1);
    float rl2 = __shfl(linv, g4 + 2);
    float rl3 = __shfl(linv, g4 + 3);

#pragma unroll
    for (int pt = 0; pt < 4; ++pt) {
        ushort4 u;
        u.x = f2bf(o[pt][0] * rl0);
        u.y = f2bf(o[pt][1] * rl1);
        u.z = f2bf(o[pt][2] * rl2);
        u.w = f2bf(o[pt][3] * rl3);
        ((ushort4*)OtF)[(((size_t)b * 32 + ct) * 4 + pt) * 64 + lane] = u;
    }
}

// ---------------------------------------------------------------------------
// 6) LayerNorm over (Cb=128, 49) per batch + tanh; writes G as bf16
//    A-fragments (scatter, inverse of repack_pf map), k>=49 zero-padded.
// ---------------------------------------------------------------------------
__global__ __launch_bounds__(256) void ln_tanh_k(
    const float* __restrict__ F0, const float* __restrict__ lnw,
    const float* __restrict__ lnb, u16* __restrict__ GF)
{
    int b = blockIdx.x, tid = threadIdx.x;
    float s = 0.f, sq = 0.f;
    for (int e = tid; e < CB * 49; e += 256) {
        int o = e / 49, k = e - o * 49;
        float v = F0[o * NB + b * 49 + k];
        s += v; sq += v * v;
    }
#pragma unroll
    for (int off = 32; off > 0; off >>= 1) {
        s  += __shfl_xor(s, off);
        sq += __shfl_xor(sq, off);
    }
    __shared__ float rs[4], rq[4];
    __shared__ float smu, srstd;
    int wv = tid >> 6;
    if ((tid & 63) == 0) { rs[wv] = s; rq[wv] = sq; }
    __syncthreads();
    if (tid == 0) {
        float S = rs[0] + rs[1] + rs[2] + rs[3];
        float Q = rq[0] + rq[1] + rq[2] + rq[3];
        float mu = S / 6272.f;
        float v  = Q / 6272.f - mu * mu;
        smu = mu; srstd = rsqrtf(v + 1e-5f);
    }
    __syncthreads();
    float mu = smu, rstd = srstd;
    for (int e = tid; e < CB * 49; e += 256) {
        int o = e / 49, k = e - o * 49;
        float g = tanhf((F0[o * NB + b * 49 + k] - mu) * rstd * lnw[e] + lnb[e]);
        int ct = o >> 4, rr = o & 15;
        int l  = ((rr >> 2) << 4) | (k & 15);
        int q  = k >> 4;
        GF[((((size_t)b * 8 + ct) * 4 + q) * 64 + l) * 4 + (rr & 3)] = f2bf(g);
    }
    // zero-pad fragment cols k=49..63
    for (int e = tid; e < CB * 15; e += 256) {
        int o = e / 15, k = 49 + (e % 15);
        int ct = o >> 4, rr = o & 15;
        int l  = ((rr >> 2) << 4) | (k & 15);
        GF[((((size_t)b * 8 + ct) * 4 + 3) * 64 + l) * 4 + (rr & 3)] = 0;
    }
}

// ---------------------------------------------------------------------------
// 7) dynamic depthwise 7x7 conv -- wave-per-plane, weights in SGPRs,
//    LDS skewed staging (round-8 variant: best measured, 76.6us).
// ---------------------------------------------------------------------------
#define PLS 1256
__global__ __launch_bounds__(256) void dwconv_k(
    const float* __restrict__ x, const float* __restrict__ KernT,
    float* __restrict__ out)
{
    __shared__ float xs[4 * PLS];     // 20096 B
    int tid  = threadIdx.x;
    int lane = tid & 63;
    int wid  = tid >> 6;
    int P    = blockIdx.x * 4 + wid;  // plane = b*512 + c, grid exact
    int b = P >> 9, c = P & 511;
    float* pl = &xs[wid * PLS];

    // zero own plane (covers pad regions)
    float4* plf = (float4*)pl;
#pragma unroll
    for (int r = 0; r < 5; ++r) {
        int l = lane + 64 * r;
        if (l < PLS / 4) plf[l] = float4{0.f, 0.f, 0.f, 0.f};
    }

    // weight: lane i holds w[i]; readlane -> SGPRs (uniform per wave)
    float wvl = 0.f;
    if (lane < 49) wvl = KernT[(size_t)c * NB + b * 49 + lane];
    int wvi = __float_as_int(wvl);
    float w[49];
#pragma unroll
    for (int i = 0; i < 49; ++i)
        w[i] = __int_as_float(__builtin_amdgcn_readlane(wvi, i));

    // stage own plane: 196 quads by 64 lanes
    const float* src = x + (size_t)P * 784;
#pragma unroll
    for (int r = 0; r < 4; ++r) {
        int q = lane + 64 * r;
        if (q < 196) {
            int y = q / 7, xq = 4 * (q % 7);
            int R = y + 3;
            *(float4*)&pl[R * 36 + (((R >> 2) & 7) << 2) + xq + 4] =
                *(const float4*)(src + y * 28 + xq);
        }
    }

    if (lane >= 49) return;
    int ty = lane / 7, gx = lane - ty * 7;
    int y0 = 4 * ty, x0 = 4 * gx;
    float acc[4][4] = {};

#pragma unroll
    for (int yy = 0; yy < 10; ++yy) {
        int R = y0 + yy;
        const float* rp = &xs[wid * PLS + R * 36 + (((R >> 2) & 7) << 2) + x0];
        float4 fa = *(const float4*)(rp);
        float4 fb = *(const float4*)(rp + 4);
        float4 fc = *(const float4*)(rp + 8);
        float f[12] = {fa.x, fa.y, fa.z, fa.w, fb.x, fb.y, fb.z, fb.w,
                       fc.x, fc.y, fc.z, fc.w};
#pragma unroll
        for (int j = 0; j < 4; ++j) {
            int dy = yy - j;
            if (dy < 0 || dy > 6) continue;
#pragma unroll
            for (int dx = 0; dx < 7; ++dx) {
                float wv = w[dy * 7 + dx];
                acc[j][0] = fmaf(wv, f[dx + 1], acc[j][0]);
                acc[j][1] = fmaf(wv, f[dx + 2], acc[j][1]);
                acc[j][2] = fmaf(wv, f[dx + 3], acc[j][2]);
                acc[j][3] = fmaf(wv, f[dx + 4], acc[j][3]);
            }
        }
    }

    float* op = out + (size_t)P * 784;
#pragma unroll
    for (int j = 0; j < 4; ++j) {
        float4 o4 = {acc[j][0], acc[j][1], acc[j][2], acc[j][3]};
        *(float4*)(op + (y0 + j) * 28 + x0) = o4;
    }
}

// ---------------------------------------------------------------------------
extern "C" void kernel_launch(void* const* d_in, const int* in_sizes, int n_in,
                              void* d_out, int out_size, void* d_ws, size_t ws_size,
                              hipStream_t stream)
{
    const float* x     = (const float*)d_in[0];
    const float* bng   = (const float*)d_in[1];
    const float* bnb   = (const float*)d_in[2];
    const float* bnm   = (const float*)d_in[3];
    const float* bnv   = (const float*)d_in[4];
    const float* Wq    = (const float*)d_in[5];
    const float* Wk    = (const float*)d_in[6];
    const float* Wkern = (const float*)d_in[7];
    const float* Wf0   = (const float*)d_in[8];
    const float* bf0   = (const float*)d_in[9];
    const float* lnw   = (const float*)d_in[10];
    const float* lnb   = (const float*)d_in[11];
    const float* Wf1   = (const float*)d_in[12];
    const float* bf1   = (const float*)d_in[13];
    float* out = (float*)d_out;
    float* ws  = (float*)d_ws;

    // workspace map (float offsets), peak 6,930,432 floats = 27.7 MB
    float* pfT  = ws;                        // [0        .. 1,605,632)
    u16*   pfF  = (u16*)(ws + 1605632);      // [1,605,632.. 2,654,208)
    u16*   WqF  = (u16*)(ws + 2654208);      // [2,654,208.. 2,785,280)
    u16*   WkF  = (u16*)(ws + 2785280);      // [2,785,280.. 2,916,352)
    u16*   Wf0F = (u16*)(ws + 2916352);      // [2,916,352.. 2,949,120)
    u16*   Wf1F = (u16*)(ws + 2949120);      // [2,949,120.. 2,981,888)
    u16*   Vt   = (u16*)(ws + 2981888);      // [2,981,888.. 3,784,704)  802,816 f
    u16*   QF   = (u16*)(ws + 3784704);      // [3,784,704.. 4,833,280)
    u16*   KF   = (u16*)(ws + 4833280);      // [4,833,280.. 5,881,856)
    u16*   VF   = (u16*)(ws + 5881856);      // [5,881,856.. 6,930,432)
    u16*   OtF  = (u16*)ws;                  // reuses pfT (dead after kwv/repack)
    float* F0    = ws + 1605632;             // reuses pfF (dead after gemm_frag)
    u16*   GF    = (u16*)(ws + 2007040);     //   " (262,144 f, ends 2,269,184)
    float* KernT = ws + 3784704;             // reuses QF+KF (dead after attn)

    pool_bn_k<<<6272, 256, 0, stream>>>(x, bng, bnb, bnm, bnv, pfT);
    repack_pf_k<<<2048, 256, 0, stream>>>(pfT, pfF);
    repack_w_k<<<256, 256, 0, stream>>>(Wq, WqF, 512);
    repack_w_k<<<256, 256, 0, stream>>>(Wk, WkF, 512);
    repack_w_k<<<64, 256, 0, stream>>>(Wf0, Wf0F, 512);   // 128x512
    repack_w_k<<<64, 256, 0, stream>>>(Wf1, Wf1F, 128);   // 512x128
    kwv_k<<<6272, 256, 0, stream>>>(pfT, Wkern, Vt);
    gemm_frag_k<<<dim3(8, 64), 256, 0, stream>>>(pfF, WqF, QF);
    gemm_frag_k<<<dim3(8, 64), 256, 0, stream>>>(pfF, WkF, KF);
    repack_v_k<<<2048, 256, 0, stream>>>(Vt, VF);
    attn_mfma_k<<<dim3(8, 64), 256, 0, stream>>>(QF, KF, VF, OtF);
    fusion_frag_k<32><<<dim3(2, 64), 256, 0, stream>>>(OtF, Wf0F, F0, bf0);
    ln_tanh_k<<<64, 256, 0, stream>>>(F0, lnw, lnb, GF);
    fusion_frag_k<8><<<dim3(8, 64), 256, 0, stream>>>(GF, Wf1F, KernT, bf1);
    dwconv_k<<<8192, 256, 0, stream>>>(x, KernT, out);
}

// Round 15
// 158.824 us; speedup vs baseline: 1.6623x; 1.2351x over previous
//
#include <hip/hip_runtime.h>
#include <math.h>

#define BB   64
#define CC   512
#define P2   49
#define CB   128
#define NB   3136   // BB * P2
#define TEMPI (1.0f/40.0f)

typedef __attribute__((ext_vector_type(4))) short    bf16x4;
typedef __attribute__((ext_vector_type(4))) float    f32x4;
typedef unsigned short u16;

__device__ inline u16 f2bf(float f) {
    union { float f; unsigned u; } x{f};
    unsigned r = (x.u + 0x7FFFu + ((x.u >> 16) & 1u)) >> 16;
    return (u16)r;
}

// Verified operand rule (derived from passing QK/PV/fusion kernels):
//   a: A[m = l&15][k = (l>>4)*4+j]
//   b: B[k = (l>>4)*4+j][n = l&15]
//   d: D[m = (l>>4)*4+r][n = l&15]
__device__ inline f32x4 mfma16x16(bf16x4 a, bf16x4 b, f32x4 c) {
#if __has_builtin(__builtin_amdgcn_mfma_f32_16x16x16bf16_1k)
    return __builtin_amdgcn_mfma_f32_16x16x16bf16_1k(a, b, c, 0, 0, 0);
#elif __has_builtin(__builtin_amdgcn_mfma_f32_16x16x16_bf16)
    return __builtin_amdgcn_mfma_f32_16x16x16_bf16(a, b, c, 0, 0, 0);
#else
    f32x4 d;
    asm("v_mfma_f32_16x16x16_bf16 %0, %1, %2, %3"
        : "=v"(d) : "v"(a), "v"(b), "v"(c));
    return d;
#endif
}

// ---------------------------------------------------------------------------
// 1) repack_all: Wq, Wk (512x512), Wf0 (128x512), Wf1 (512x128) into
//    B-operand fragments; Wkern (49x49) zero-padded to 64x64.
// ---------------------------------------------------------------------------
__global__ __launch_bounds__(256) void repack_all_k(
    const float* __restrict__ Wq, const float* __restrict__ Wk,
    const float* __restrict__ Wf0, const float* __restrict__ Wf1,
    const float* __restrict__ Wkern,
    u16* __restrict__ WqF, u16* __restrict__ WkF,
    u16* __restrict__ Wf0F, u16* __restrict__ Wf1F,
    u16* __restrict__ WkernF)
{
    int u = blockIdx.x * 256 + threadIdx.x;
    if (u >= 163840) {                      // Wkern, zero-padded
        int uu = u - 163840;
        int l = uu & 63, rest = uu >> 6;
        int ct = rest & 3, t = rest >> 2;
        int o  = t * 16 + (l & 15);
        int c0 = ct * 16 + ((l >> 4) << 2);
        ushort4 v;
        v.x = (o < 49 && c0 + 0 < 49) ? f2bf(Wkern[o * 49 + c0 + 0]) : 0;
        v.y = (o < 49 && c0 + 1 < 49) ? f2bf(Wkern[o * 49 + c0 + 1]) : 0;
        v.z = (o < 49 && c0 + 2 < 49) ? f2bf(Wkern[o * 49 + c0 + 2]) : 0;
        v.w = (o < 49 && c0 + 3 < 49) ? f2bf(Wkern[o * 49 + c0 + 3]) : 0;
        ((ushort4*)WkernF)[uu] = v;
        return;
    }
    const float* W; u16* dst; int K, uu;
    if (u < 65536)       { W = Wq;  dst = WqF;  K = 512; uu = u; }
    else if (u < 131072) { W = Wk;  dst = WkF;  K = 512; uu = u - 65536; }
    else if (u < 147456) { W = Wf0; dst = Wf0F; K = 512; uu = u - 131072; }
    else                 { W = Wf1; dst = Wf1F; K = 128; uu = u - 147456; }
    int l = uu & 63, rest = uu >> 6;
    int KT = K >> 4;
    int ct = rest % KT, t = rest / KT;
    int o  = t * 16 + (l & 15);
    int c0 = ct * 16 + ((l >> 4) << 2);
    float4 v = *(const float4*)(W + (size_t)o * K + c0);
    ushort4 w;
    w.x = f2bf(v.x); w.y = f2bf(v.y); w.z = f2bf(v.z); w.w = f2bf(v.w);
    ((ushort4*)dst)[uu] = w;
}

// ---------------------------------------------------------------------------
// 2) prep: pool+BN -> LDS pf[128][50]; emit pfF fragments (repack_pf map)
//    and VF fragments via MFMA (V = pf x Wkern^T).
//    Stage-3 FIX (round-14 bug: output transposed): operands swapped so
//    A = pf-frag (A[m=c via lo][k=p via hi+j]), B = WkernF
//    (B[k=p via hi+j][n=kpos via lo]) -> D[c via hi+r][kpos via lo] == VF map.
// ---------------------------------------------------------------------------
__global__ __launch_bounds__(256) void prep_k(
    const float* __restrict__ x, const float* __restrict__ g,
    const float* __restrict__ be, const float* __restrict__ mu,
    const float* __restrict__ var, const u16* __restrict__ WkernF,
    u16* __restrict__ pfF, u16* __restrict__ VF)
{
    __shared__ float pf[128][50];
    int tid = threadIdx.x;
    int bg  = blockIdx.x;          // b*4 + grp
    int b = bg >> 2, grp = bg & 3;
    int cbase = grp * 128;

    // stage 1: pool + BN
    for (int i = tid; i < 128 * 49; i += 256) {
        int cl = i / 49, p = i - cl * 49;
        int c = cbase + cl;
        const float* basep = x + ((size_t)(b * 512 + c)) * 784
                             + (p / 7) * 4 * 28 + (p % 7) * 4;
        float s = 0.f;
#pragma unroll
        for (int r = 0; r < 4; ++r) {
            float4 v = *(const float4*)(basep + r * 28);
            s += v.x + v.y + v.z + v.w;
        }
        s *= (1.f / 16.f);
        float sc = g[c] * rsqrtf(var[c] + 1e-5f);
        pf[cl][p] = (s - mu[c]) * sc + be[c];
    }
    __syncthreads();

    // stage 2: pfF fragments (verbatim repack_pf map, 2048 units)
    for (int u = tid; u < 2048; u += 256) {
        int l = u & 63, q = (u >> 6) & 3, ctl = u >> 8;
        int p   = q * 16 + (l & 15);
        int c0l = ctl * 16 + ((l >> 4) << 2);
        ushort4 o;
        if (p < 49) {
            o.x = f2bf(pf[c0l + 0][p]); o.y = f2bf(pf[c0l + 1][p]);
            o.z = f2bf(pf[c0l + 2][p]); o.w = f2bf(pf[c0l + 3][p]);
        } else { o.x = o.y = o.z = o.w = 0; }
        ((ushort4*)pfF)[((size_t)(b * 32 + grp * 8 + ctl) * 4 + q) * 64 + l] = o;
    }

    // stage 3 (FIXED): VF via MFMA with pf as A-operand, WkernF as B-operand.
    int lane = tid & 63, w = tid >> 6;
    const bf16x4* WkF4 = (const bf16x4*)WkernF;
#pragma unroll
    for (int i = 0; i < 8; ++i) {
        int dt  = w * 8 + i;           // 32 D-tiles / 4 waves
        int ct2 = dt >> 2, tk = dt & 3;
        int cc  = ct2 * 16 + (lane & 15);   // channel from LO (A's m index)
        f32x4 acc = (f32x4)0.f;
#pragma unroll
        for (int ptp = 0; ptp < 4; ++ptp) {
            bf16x4 af;                       // A[m=cc][k=p via hi+j]
#pragma unroll
            for (int j = 0; j < 4; ++j) {
                int p = ptp * 16 + ((lane >> 4) << 2) + j;
                af[j] = (short)((p < 49) ? f2bf(pf[cc][p]) : 0);
            }
            bf16x4 bw = WkF4[(tk * 4 + ptp) * 64 + lane];  // B[k=p][n=kpos]
            acc = mfma16x16(af, bw, acc);
        }
        // acc[r] lane l = Vt[c = ct2*16+(l>>4)*4+r][kpos = tk*16+(l&15)]
        ushort4 o;
        o.x = f2bf(acc[0]); o.y = f2bf(acc[1]);
        o.z = f2bf(acc[2]); o.w = f2bf(acc[3]);
        ((ushort4*)VF)[((size_t)(b * 32 + grp * 8 + ct2) * 4 + tk) * 64 + lane] = o;
    }
}

// ---------------------------------------------------------------------------
// 3) Q and K fragment GEMMs in one launch (z selects Wq/Wk).
// ---------------------------------------------------------------------------
__global__ __launch_bounds__(256) void gemm_qk_k(
    const u16* __restrict__ pfF, const u16* __restrict__ WqF,
    const u16* __restrict__ WkF, u16* __restrict__ QF, u16* __restrict__ KF)
{
    const u16* WF   = blockIdx.z ? WkF : WqF;
    u16*       dstF = blockIdx.z ? KF : QF;
    int tid  = threadIdx.x;
    int lane = tid & 63;
    int w    = tid >> 6;
    int b    = blockIdx.y;
    int t    = blockIdx.x * 4 + w;

    const bf16x4* Ab = (const bf16x4*)pfF + (size_t)b * 8192 + lane;
    const bf16x4* Bw = (const bf16x4*)WF + (size_t)t * 2048 + lane;

    f32x4 acc[4];
#pragma unroll
    for (int q = 0; q < 4; ++q) acc[q] = (f32x4)0.f;

#pragma unroll
    for (int ct = 0; ct < 32; ++ct) {
        bf16x4 wv = Bw[ct * 64];
        bf16x4 a0 = Ab[(ct * 4 + 0) * 64];
        bf16x4 a1 = Ab[(ct * 4 + 1) * 64];
        bf16x4 a2 = Ab[(ct * 4 + 2) * 64];
        bf16x4 a3 = Ab[(ct * 4 + 3) * 64];
        acc[0] = mfma16x16(a0, wv, acc[0]);
        acc[1] = mfma16x16(a1, wv, acc[1]);
        acc[2] = mfma16x16(a2, wv, acc[2]);
        acc[3] = mfma16x16(a3, wv, acc[3]);
    }

#pragma unroll
    for (int q = 0; q < 4; ++q) {
        ushort4 u;
        u.x = f2bf(acc[q][0]); u.y = f2bf(acc[q][1]);
        u.z = f2bf(acc[q][2]); u.w = f2bf(acc[q][3]);
        ((ushort4*)dstF)[(((size_t)b * 32 + t) * 4 + q) * 64 + lane] = u;
    }
}

// ---------------------------------------------------------------------------
// 4) MFMA flash attention; output as bf16 A-fragments (verified).
// ---------------------------------------------------------------------------
__global__ __launch_bounds__(256) void attn_mfma_k(
    const u16* __restrict__ QF, const u16* __restrict__ KF,
    const u16* __restrict__ VF, u16* __restrict__ OtF)
{
    int tid  = threadIdx.x;
    int lane = tid & 63;
    int w    = tid >> 6;
    int b    = blockIdx.y;
    int ct   = blockIdx.x * 4 + w;

    const bf16x4* QFp = (const bf16x4*)QF + (size_t)b * 8192 + ct * 256 + lane;
    const bf16x4* KFp = (const bf16x4*)KF + (size_t)b * 8192 + lane;
    const bf16x4* VFp = (const bf16x4*)VF + (size_t)b * 8192 + lane;

    bf16x4 qf[4];
#pragma unroll
    for (int q = 0; q < 4; ++q) qf[q] = QFp[q * 64];

    f32x4 o[4];
#pragma unroll
    for (int pt = 0; pt < 4; ++pt) o[pt] = (f32x4)0.f;
    float lsum = 0.f;

    bf16x4 kf[4], vf[4], kn[4], vn[4];
#pragma unroll
    for (int q = 0; q < 4; ++q) { kf[q] = KFp[q * 64]; vf[q] = VFp[q * 64]; }

    for (int t = 0; t < 32; ++t) {
        if (t < 31) {
            const bf16x4* kp = KFp + (t + 1) * 256;
            const bf16x4* vp = VFp + (t + 1) * 256;
#pragma unroll
            for (int q = 0; q < 4; ++q) { kn[q] = kp[q * 64]; vn[q] = vp[q * 64]; }
        }
        f32x4 s = (f32x4)0.f;
#pragma unroll
        for (int q = 0; q < 4; ++q) s = mfma16x16(kf[q], qf[q], s);

        bf16x4 pa;
#pragma unroll
        for (int r = 0; r < 4; ++r) {
            float pe = __expf(s[r] * TEMPI);
            lsum += pe;
            pa[r] = (short)f2bf(pe);
        }
#pragma unroll
        for (int pt = 0; pt < 4; ++pt) o[pt] = mfma16x16(pa, vf[pt], o[pt]);

#pragma unroll
        for (int q = 0; q < 4; ++q) { kf[q] = kn[q]; vf[q] = vn[q]; }
    }

    lsum += __shfl_xor(lsum, 16);
    lsum += __shfl_xor(lsum, 32);
    float linv = 1.f / lsum;

    int g4 = (lane >> 4) << 2;
    float rl0 = __shfl(linv, g4 + 0);
    float rl1 = __shfl(linv, g4 + 1);
    float rl2 = __shfl(linv, g4 + 2);
    float rl3 = __shfl(linv, g4 + 3);

#pragma unroll
    for (int pt = 0; pt < 4; ++pt) {
        ushort4 u;
        u.x = f2bf(o[pt][0] * rl0);
        u.y = f2bf(o[pt][1] * rl1);
        u.z = f2bf(o[pt][2] * rl2);
        u.w = f2bf(o[pt][3] * rl3);
        ((ushort4*)OtF)[(((size_t)b * 32 + ct) * 4 + pt) * 64 + lane] = u;
    }
}

// ---------------------------------------------------------------------------
// 5) fusion0 + LayerNorm + tanh fused, per batch; 512 threads (wave w = t).
// ---------------------------------------------------------------------------
__global__ __launch_bounds__(512) void f0ln_k(
    const u16* __restrict__ OtF, const u16* __restrict__ Wf0F,
    const float* __restrict__ bf0, const float* __restrict__ lnw,
    const float* __restrict__ lnb, u16* __restrict__ GF)
{
    __shared__ float F0[128][50];
    __shared__ float rs[8], rq[8];
    __shared__ float smu, srstd;
    int tid  = threadIdx.x;
    int lane = tid & 63, w = tid >> 6;   // w = output c-tile 0..7
    int b = blockIdx.x;

    const bf16x4* Ab = (const bf16x4*)OtF + (size_t)b * 8192 + lane;
    const bf16x4* Bw = (const bf16x4*)Wf0F + (size_t)w * 2048 + lane;

    f32x4 acc[4];
#pragma unroll
    for (int q = 0; q < 4; ++q) acc[q] = (f32x4)0.f;
#pragma unroll
    for (int ct = 0; ct < 32; ++ct) {
        bf16x4 wv = Bw[ct * 64];
        bf16x4 a0 = Ab[(ct * 4 + 0) * 64];
        bf16x4 a1 = Ab[(ct * 4 + 1) * 64];
        bf16x4 a2 = Ab[(ct * 4 + 2) * 64];
        bf16x4 a3 = Ab[(ct * 4 + 3) * 64];
        acc[0] = mfma16x16(a0, wv, acc[0]);
        acc[1] = mfma16x16(a1, wv, acc[1]);
        acc[2] = mfma16x16(a2, wv, acc[2]);
        acc[3] = mfma16x16(a3, wv, acc[3]);
    }

    int c = w * 16 + (lane & 15);
    float bb = bf0[c];
    int g4 = (lane >> 4) << 2;
#pragma unroll
    for (int q = 0; q < 4; ++q)
#pragma unroll
        for (int r = 0; r < 4; ++r) {
            int p = q * 16 + g4 + r;
            if (p < 49) F0[c][p] = acc[q][r] + bb;
        }
    __syncthreads();

    float s = 0.f, sq = 0.f;
    for (int e = tid; e < CB * 49; e += 512) {
        int o = e / 49, k = e - o * 49;
        float v = F0[o][k];
        s += v; sq += v * v;
    }
#pragma unroll
    for (int off = 32; off > 0; off >>= 1) {
        s  += __shfl_xor(s, off);
        sq += __shfl_xor(sq, off);
    }
    if ((tid & 63) == 0) { rs[w] = s; rq[w] = sq; }
    __syncthreads();
    if (tid == 0) {
        float S = 0.f, Q = 0.f;
#pragma unroll
        for (int i = 0; i < 8; ++i) { S += rs[i]; Q += rq[i]; }
        float mu = S / 6272.f;
        float v  = Q / 6272.f - mu * mu;
        smu = mu; srstd = rsqrtf(v + 1e-5f);
    }
    __syncthreads();
    float mu = smu, rstd = srstd;

    for (int u = tid; u < 2048; u += 512) {
        int l = u & 63, q = (u >> 6) & 3, ct = u >> 8;
        int c0 = ct * 16 + ((l >> 4) << 2);
        int k  = q * 16 + (l & 15);
        ushort4 o;
        if (k < 49) {
            o.x = f2bf(tanhf((F0[c0+0][k] - mu) * rstd * lnw[(c0+0)*49+k] + lnb[(c0+0)*49+k]));
            o.y = f2bf(tanhf((F0[c0+1][k] - mu) * rstd * lnw[(c0+1)*49+k] + lnb[(c0+1)*49+k]));
            o.z = f2bf(tanhf((F0[c0+2][k] - mu) * rstd * lnw[(c0+2)*49+k] + lnb[(c0+2)*49+k]));
            o.w = f2bf(tanhf((F0[c0+3][k] - mu) * rstd * lnw[(c0+3)*49+k] + lnb[(c0+3)*49+k]));
        } else { o.x = o.y = o.z = o.w = 0; }
        ((ushort4*)GF)[(((size_t)b * 8 + ct) * 4 + q) * 64 + l] = o;
    }
}

// ---------------------------------------------------------------------------
// 6) fusion1 (fragment GEMM, fp32 out + bias; corrected epilogue map).
// ---------------------------------------------------------------------------
template <int KT>
__global__ __launch_bounds__(256) void fusion_frag_k(
    const u16* __restrict__ AF, const u16* __restrict__ WF,
    float* __restrict__ Cout, const float* __restrict__ bias)
{
    int tid  = threadIdx.x;
    int lane = tid & 63;
    int w    = tid >> 6;
    int b    = blockIdx.y;
    int t    = blockIdx.x * 4 + w;

    const bf16x4* Ab = (const bf16x4*)AF + (size_t)b * (KT * 256) + lane;
    const bf16x4* Bw = (const bf16x4*)WF + (size_t)t * (KT * 64) + lane;

    f32x4 acc[4];
#pragma unroll
    for (int q = 0; q < 4; ++q) acc[q] = (f32x4)0.f;

#pragma unroll
    for (int ct = 0; ct < KT; ++ct) {
        bf16x4 wv = Bw[ct * 64];
        bf16x4 a0 = Ab[(ct * 4 + 0) * 64];
        bf16x4 a1 = Ab[(ct * 4 + 1) * 64];
        bf16x4 a2 = Ab[(ct * 4 + 2) * 64];
        bf16x4 a3 = Ab[(ct * 4 + 3) * 64];
        acc[0] = mfma16x16(a0, wv, acc[0]);
        acc[1] = mfma16x16(a1, wv, acc[1]);
        acc[2] = mfma16x16(a2, wv, acc[2]);
        acc[3] = mfma16x16(a3, wv, acc[3]);
    }

    int c = t * 16 + (lane & 15);
    float bb = bias[c];
    float* op = Cout + (size_t)c * NB + b * 49;
    int g4 = (lane >> 4) << 2;
#pragma unroll
    for (int q = 0; q < 4; ++q) {
#pragma unroll
        for (int r = 0; r < 4; ++r) {
            int p = q * 16 + g4 + r;
            if (p < 49) op[p] = acc[q][r] + bb;
        }
    }
}

// ---------------------------------------------------------------------------
// 7) dynamic depthwise 7x7 conv (round-8/13 best: wave-per-plane, SGPR
//    weights, skewed LDS staging).
// ---------------------------------------------------------------------------
#define PLS 1256
__global__ __launch_bounds__(256) void dwconv_k(
    const float* __restrict__ x, const float* __restrict__ KernT,
    float* __restrict__ out)
{
    __shared__ float xs[4 * PLS];
    int tid  = threadIdx.x;
    int lane = tid & 63;
    int wid  = tid >> 6;
    int P    = blockIdx.x * 4 + wid;
    int b = P >> 9, c = P & 511;
    float* pl = &xs[wid * PLS];

    float4* plf = (float4*)pl;
#pragma unroll
    for (int r = 0; r < 5; ++r) {
        int l = lane + 64 * r;
        if (l < PLS / 4) plf[l] = float4{0.f, 0.f, 0.f, 0.f};
    }

    float wvl = 0.f;
    if (lane < 49) wvl = KernT[(size_t)c * NB + b * 49 + lane];
    int wvi = __float_as_int(wvl);
    float w[49];
#pragma unroll
    for (int i = 0; i < 49; ++i)
        w[i] = __int_as_float(__builtin_amdgcn_readlane(wvi, i));

    const float* src = x + (size_t)P * 784;
#pragma unroll
    for (int r = 0; r < 4; ++r) {
        int q = lane + 64 * r;
        if (q < 196) {
            int y = q / 7, xq = 4 * (q % 7);
            int R = y + 3;
            *(float4*)&pl[R * 36 + (((R >> 2) & 7) << 2) + xq + 4] =
                *(const float4*)(src + y * 28 + xq);
        }
    }

    if (lane >= 49) return;
    int ty = lane / 7, gx = lane - ty * 7;
    int y0 = 4 * ty, x0 = 4 * gx;
    float acc[4][4] = {};

#pragma unroll
    for (int yy = 0; yy < 10; ++yy) {
        int R = y0 + yy;
        const float* rp = &pl[R * 36 + (((R >> 2) & 7) << 2) + x0];
        float4 fa = *(const float4*)(rp);
        float4 fb = *(const float4*)(rp + 4);
        float4 fc = *(const float4*)(rp + 8);
        float f[12] = {fa.x, fa.y, fa.z, fa.w, fb.x, fb.y, fb.z, fb.w,
                       fc.x, fc.y, fc.z, fc.w};
#pragma unroll
        for (int j = 0; j < 4; ++j) {
            int dy = yy - j;
            if (dy < 0 || dy > 6) continue;
#pragma unroll
            for (int dx = 0; dx < 7; ++dx) {
                float wv = w[dy * 7 + dx];
                acc[j][0] = fmaf(wv, f[dx + 1], acc[j][0]);
                acc[j][1] = fmaf(wv, f[dx + 2], acc[j][1]);
                acc[j][2] = fmaf(wv, f[dx + 3], acc[j][2]);
                acc[j][3] = fmaf(wv, f[dx + 4], acc[j][3]);
            }
        }
    }

    float* op = out + (size_t)P * 784;
#pragma unroll
    for (int j = 0; j < 4; ++j) {
        float4 o4 = {acc[j][0], acc[j][1], acc[j][2], acc[j][3]};
        *(float4*)(op + (y0 + j) * 28 + x0) = o4;
    }
}

// ---------------------------------------------------------------------------
extern "C" void kernel_launch(void* const* d_in, const int* in_sizes, int n_in,
                              void* d_out, int out_size, void* d_ws, size_t ws_size,
                              hipStream_t stream)
{
    const float* x     = (const float*)d_in[0];
    const float* bng   = (const float*)d_in[1];
    const float* bnb   = (const float*)d_in[2];
    const float* bnm   = (const float*)d_in[3];
    const float* bnv   = (const float*)d_in[4];
    const float* Wq    = (const float*)d_in[5];
    const float* Wk    = (const float*)d_in[6];
    const float* Wkern = (const float*)d_in[7];
    const float* Wf0   = (const float*)d_in[8];
    const float* bf0   = (const float*)d_in[9];
    const float* lnw   = (const float*)d_in[10];
    const float* lnb   = (const float*)d_in[11];
    const float* Wf1   = (const float*)d_in[12];
    const float* bf1   = (const float*)d_in[13];
    float* out = (float*)d_out;
    float* ws  = (float*)d_ws;

    // workspace (float-equiv offsets), peak 5,834,752 f = 23.3 MB
    u16* pfF    = (u16*)(ws + 0);            // [0 .. 1,048,576)
    u16* VF     = (u16*)(ws + 1048576);      // [1,048,576 .. 2,097,152)
    u16* WqF    = (u16*)(ws + 2097152);      // [2,097,152 .. 2,228,224)
    u16* WkF    = (u16*)(ws + 2228224);      // [2,228,224 .. 2,359,296)
    u16* Wf0F   = (u16*)(ws + 2359296);      // [2,359,296 .. 2,392,064)
    u16* Wf1F   = (u16*)(ws + 2392064);      // [2,392,064 .. 2,424,832)
    u16* WkernF = (u16*)(ws + 2424832);      // [2,424,832 .. 2,426,880)
    u16* QF     = (u16*)(ws + 2426880);      // [2,426,880 .. 3,475,456)
    u16* KF     = (u16*)(ws + 3475456);      // [3,475,456 .. 4,524,032)
    u16* OtF    = (u16*)(ws + 4524032);      // [4,524,032 .. 5,572,608)
    u16* GF     = (u16*)(ws + 5572608);      // [5,572,608 .. 5,834,752)
    float* KernT = ws + 2426880;             // reuses QF+KF (dead after attn)

    repack_all_k<<<644, 256, 0, stream>>>(Wq, Wk, Wf0, Wf1, Wkern,
                                          WqF, WkF, Wf0F, Wf1F, WkernF);
    prep_k<<<256, 256, 0, stream>>>(x, bng, bnb, bnm, bnv, WkernF, pfF, VF);
    gemm_qk_k<<<dim3(8, 64, 2), 256, 0, stream>>>(pfF, WqF, WkF, QF, KF);
    attn_mfma_k<<<dim3(8, 64), 256, 0, stream>>>(QF, KF, VF, OtF);
    f0ln_k<<<64, 512, 0, stream>>>(OtF, Wf0F, bf0, lnw, lnb, GF);
    fusion_frag_k<8><<<dim3(8, 64), 256, 0, stream>>>(GF, Wf1F, KernT, bf1);
    dwconv_k<<<8192, 256, 0, stream>>>(x, KernT, out);
}